// Round 1
// baseline (366.162 us; speedup 1.0000x reference)
//
#include <hip/hip_runtime.h>
#include <math.h>

typedef __attribute__((ext_vector_type(2))) float f32x2;

#define BM 64
#define BK 32
#define NT 256
#define M_TOTAL 16384
#define K_DIM 2048
#define E_DIM 64

__global__ __launch_bounds__(NT, 1) void router_topk_kernel(
    const float* __restrict__ x,
    const float* __restrict__ router_w,
    const float* __restrict__ noise_w,
    const float* __restrict__ router_b,
    const float* __restrict__ noise_b,
    const float* __restrict__ noise_u,
    float* __restrict__ out)
{
    __shared__ union {
        struct { float As[BK][68]; float Bs[BK][132]; } s;
        struct { float Cs[64][132]; float p1v[64]; float p2v[64]; int i1v[64]; int i2v[64]; } e;
    } sm;

    const int t = threadIdx.x;
    const int rowBase = blockIdx.x * BM;

    const int kq = t & 7;    // k-quad within chunk (0..7)
    const int fr = t >> 3;   // staging row/col (0..31)
    const int tx = t & 15;   // micro-tile col group
    const int ty = t >> 4;   // micro-tile row group (0..15)

    const float* gA0 = x + (size_t)(rowBase + fr) * K_DIM + kq * 4;
    const float* gA1 = gA0 + (size_t)32 * K_DIM;
    const float* gB0 = router_w + (size_t)fr * K_DIM + kq * 4;
    const float* gB1 = gB0 + (size_t)32 * K_DIM;
    const float* gB2 = noise_w + (size_t)fr * K_DIM + kq * 4;
    const float* gB3 = gB2 + (size_t)32 * K_DIM;

    f32x2 acc[4][4];
    #pragma unroll
    for (int i = 0; i < 4; ++i)
        #pragma unroll
        for (int j = 0; j < 4; ++j) { acc[i][j].x = 0.0f; acc[i][j].y = 0.0f; }

    float4 aR0, aR1, bR0, bR1, bR2, bR3;
    // prefetch chunk 0
    aR0 = *(const float4*)(gA0);
    aR1 = *(const float4*)(gA1);
    bR0 = *(const float4*)(gB0);
    bR1 = *(const float4*)(gB1);
    bR2 = *(const float4*)(gB2);
    bR3 = *(const float4*)(gB3);

    const int NCHUNK = K_DIM / BK;  // 64
    for (int c = 0; c < NCHUNK; ++c) {
        __syncthreads();
        // stage regs -> LDS (transposed: [k][m])
        #pragma unroll
        for (int j = 0; j < 4; ++j) {
            const int kk = kq * 4 + j;
            sm.s.As[kk][fr]      = ((const float*)&aR0)[j];
            sm.s.As[kk][fr + 32] = ((const float*)&aR1)[j];
            sm.s.Bs[kk][fr]      = ((const float*)&bR0)[j];
            sm.s.Bs[kk][fr + 32] = ((const float*)&bR1)[j];
            sm.s.Bs[kk][fr + 64] = ((const float*)&bR2)[j];
            sm.s.Bs[kk][fr + 96] = ((const float*)&bR3)[j];
        }
        __syncthreads();

        if (c + 1 < NCHUNK) {
            const int off = (c + 1) * BK;
            aR0 = *(const float4*)(gA0 + off);
            aR1 = *(const float4*)(gA1 + off);
            bR0 = *(const float4*)(gB0 + off);
            bR1 = *(const float4*)(gB1 + off);
            bR2 = *(const float4*)(gB2 + off);
            bR3 = *(const float4*)(gB3 + off);
        }

        #pragma unroll
        for (int k = 0; k < BK; ++k) {
            const float4 a4  = *(const float4*)&sm.s.As[k][ty * 4];
            const float4 b4a = *(const float4*)&sm.s.Bs[k][tx * 4];
            const float4 b4b = *(const float4*)&sm.s.Bs[k][64 + tx * 4];
            f32x2 b0, b1, b2, b3;
            b0.x = b4a.x; b0.y = b4a.y;
            b1.x = b4a.z; b1.y = b4a.w;
            b2.x = b4b.x; b2.y = b4b.y;
            b3.x = b4b.z; b3.y = b4b.w;
            const float ar[4] = {a4.x, a4.y, a4.z, a4.w};
            #pragma unroll
            for (int i = 0; i < 4; ++i) {
                f32x2 av; av.x = ar[i]; av.y = ar[i];
                acc[i][0] += av * b0;
                acc[i][1] += av * b1;
                acc[i][2] += av * b2;
                acc[i][3] += av * b3;
            }
        }
    }

    // ---- epilogue ----
    __syncthreads();   // everyone done reading As/Bs; safe to reuse as Cs
    #pragma unroll
    for (int i = 0; i < 4; ++i) {
        const int r = ty * 4 + i;
        float4 v0, v1;
        v0.x = acc[i][0].x; v0.y = acc[i][0].y; v0.z = acc[i][1].x; v0.w = acc[i][1].y;
        v1.x = acc[i][2].x; v1.y = acc[i][2].y; v1.z = acc[i][3].x; v1.w = acc[i][3].y;
        *(float4*)&sm.e.Cs[r][tx * 4]      = v0;
        *(float4*)&sm.e.Cs[r][64 + tx * 4] = v1;
    }
    __syncthreads();

    if (t < 64) {
        const int r = t;
        const int grow = rowBase + r;
        const float* urow = noise_u + (size_t)grow * E_DIM;
        float v1 = -3.0e38f, v2 = -3.0e38f;
        int i1 = 0, i2 = 0;
        for (int e = 0; e < E_DIM; ++e) {
            const float lg = sm.e.Cs[r][e] + router_b[e];
            const float nz = sm.e.Cs[r][64 + e] + noise_b[e];
            // softplus(nz) = max(nz,0) + log1p(exp(-|nz|))   (matches jax logaddexp form)
            const float sp = fmaxf(nz, 0.0f) + log1pf(expf(-fabsf(nz)));
            const float nv = lg + sp * urow[e];
            if (nv > v1) { v2 = v1; i2 = i1; v1 = nv; i1 = e; }
            else if (nv > v2) { v2 = nv; i2 = e; }
        }
        const float e2 = expf(v2 - v1);
        const float denom = 1.0f + e2;   // other 62 slots: exp(-1e30 - m) == 0
        sm.e.p1v[r] = 1.0f / denom;
        sm.e.p2v[r] = e2 / denom;
        sm.e.i1v[r] = i1;
        sm.e.i2v[r] = i2;
        float2 idx2;
        idx2.x = (float)i1;
        idx2.y = (float)i2;
        *(float2*)&out[(size_t)M_TOTAL * E_DIM + (size_t)grow * 2] = idx2;
    }
    __syncthreads();

    // cooperative write of sparse softmax: 64 rows x 64 experts, 16 floats/thread
    {
        const int r  = t >> 2;
        const int eb = (t & 3) * 16;
        const int grow = rowBase + r;
        const int i1 = sm.e.i1v[r];
        const int i2 = sm.e.i2v[r];
        const float p1 = sm.e.p1v[r];
        const float p2 = sm.e.p2v[r];
        float* orow = out + (size_t)grow * E_DIM;
        #pragma unroll
        for (int g = 0; g < 4; ++g) {
            const int e0 = eb + g * 4;
            float4 v;
            v.x = (e0 + 0 == i1) ? p1 : (e0 + 0 == i2) ? p2 : 0.0f;
            v.y = (e0 + 1 == i1) ? p1 : (e0 + 1 == i2) ? p2 : 0.0f;
            v.z = (e0 + 2 == i1) ? p1 : (e0 + 2 == i2) ? p2 : 0.0f;
            v.w = (e0 + 3 == i1) ? p1 : (e0 + 3 == i2) ? p2 : 0.0f;
            *(float4*)&orow[e0] = v;
        }
    }
}

extern "C" void kernel_launch(void* const* d_in, const int* in_sizes, int n_in,
                              void* d_out, int out_size, void* d_ws, size_t ws_size,
                              hipStream_t stream) {
    const float* x  = (const float*)d_in[0];
    const float* rw = (const float*)d_in[1];
    const float* rb = (const float*)d_in[2];
    const float* nw = (const float*)d_in[3];
    const float* nb = (const float*)d_in[4];
    const float* nu = (const float*)d_in[5];
    float* out = (float*)d_out;
    (void)in_sizes; (void)n_in; (void)out_size; (void)d_ws; (void)ws_size;

    hipLaunchKernelGGL(router_topk_kernel, dim3(M_TOTAL / BM), dim3(NT), 0, stream,
                       x, rw, nw, rb, nb, nu, out);
}